// Round 2
// 266.509 us; speedup vs baseline: 1.1253x; 1.1253x over previous
//
#include <hip/hip_runtime.h>
#include <math.h>

static constexpr int Bb = 4;
static constexpr int Nn = 512;
static constexpr int Dd = 1024;
static constexpr int Ee = 8;
static constexpr int Hh = 4096;
static constexpr float CAP = 4.0f;   // float(int(1.0 * B))
static constexpr float EPS = 1e-6f;

static constexpr int P1S = 32;   // ffn1 k-splits (depth 32)
static constexpr int P2S = 32;   // ffn2 k-splits (depth 128)

// ws layout (float offsets):
//   [0,256)             bmask (int, one per gate block; fully written -> no memset)
//   [256,288)           gate0
//   [320,352)           gs
//   [512,131584)        hT[32][4096]   (token-major)
//   [132096,4326400)    p1[32*32][4096]
//   [4326400,5374976)   p2[32*32][1024]

// =====================================================================
// K1: blocks [0,256) ffn1 k-split GEMM (stages x directly)
//     blocks [256,512) gating (8 tokens/block, per-block mask)
//     blocks [512,768) zero dead output rows
// =====================================================================
__global__ __launch_bounds__(256) void k1_gate_ffn1(
    const float* __restrict__ x, const float* __restrict__ wg,
    const float* __restrict__ bg, const float* __restrict__ w1,
    int* __restrict__ bmask, float* __restrict__ gate0,
    float* __restrict__ p1, float* __restrict__ out)
{
    __shared__ float smem[8 * 1028 + 16];   // 32.96 KB (gate); ffn1 uses first 1024
    const int blk = blockIdx.x;
    const int tid = threadIdx.x;

    if (blk < 256) {
        // ---- ffn1 partial GEMM: h-chunk hc (512 wide), k-chunk ks (32 deep) ----
        const int hc = blk & 7, ks = blk >> 3, k0 = ks * 32;
        {   // stage x[32 live tokens][k0..k0+32) -> smem as [k][t]
            const int t = tid >> 3, q = tid & 7;
            const int row = (t >> 3) * Nn + (t & 7);       // token t = b*8+n
            float4 v = *(const float4*)(x + (size_t)row * Dd + k0 + q * 4);
            smem[(q * 4 + 0) * 32 + t] = v.x;
            smem[(q * 4 + 1) * 32 + t] = v.y;
            smem[(q * 4 + 2) * 32 + t] = v.z;
            smem[(q * 4 + 3) * 32 + t] = v.w;
        }
        __syncthreads();
        const int h = hc * 512 + tid * 2;
        const float* wp = w1 + (size_t)k0 * Hh + h;        // expert 0: w1[d][h]
        float2 acc[32];
#pragma unroll
        for (int t = 0; t < 32; ++t) acc[t] = make_float2(0.f, 0.f);
#pragma unroll
        for (int half = 0; half < 2; ++half) {
            float2 wbuf[16];
#pragma unroll
            for (int kk = 0; kk < 16; ++kk)
                wbuf[kk] = *(const float2*)(wp + (size_t)(half * 16 + kk) * Hh);
#pragma unroll
            for (int kk = 0; kk < 16; ++kk) {
                const float4* xrow = (const float4*)(smem + (half * 16 + kk) * 32);
                const float2 w = wbuf[kk];
#pragma unroll
                for (int t4 = 0; t4 < 8; ++t4) {
                    float4 xv = xrow[t4];
                    acc[t4 * 4 + 0].x = fmaf(xv.x, w.x, acc[t4 * 4 + 0].x);
                    acc[t4 * 4 + 0].y = fmaf(xv.x, w.y, acc[t4 * 4 + 0].y);
                    acc[t4 * 4 + 1].x = fmaf(xv.y, w.x, acc[t4 * 4 + 1].x);
                    acc[t4 * 4 + 1].y = fmaf(xv.y, w.y, acc[t4 * 4 + 1].y);
                    acc[t4 * 4 + 2].x = fmaf(xv.z, w.x, acc[t4 * 4 + 2].x);
                    acc[t4 * 4 + 2].y = fmaf(xv.z, w.y, acc[t4 * 4 + 2].y);
                    acc[t4 * 4 + 3].x = fmaf(xv.w, w.x, acc[t4 * 4 + 3].x);
                    acc[t4 * 4 + 3].y = fmaf(xv.w, w.y, acc[t4 * 4 + 3].y);
                }
            }
        }
        float* o = p1 + ((size_t)ks * 32) * Hh + h;
#pragma unroll
        for (int t = 0; t < 32; ++t) { *(float2*)o = acc[t]; o += Hh; }
    } else if (blk < 512) {
        // ---- gating: block g handles tokens g*8 .. g*8+7 (all in batch g>>6) ----
        const int g = blk - 256;
        for (int i = tid; i < Dd * Ee; i += 256)
            smem[(i & 7) * 1028 + (i >> 3)] = wg[i];       // wg[d][e] -> [e][d] padded
        int* bb = (int*)&smem[8224];
        __syncthreads();
        const int wave = tid >> 6, lane = tid & 63;
        for (int j = 0; j < 2; ++j) {
            const int sub = wave + 4 * j;                  // 0..7
            const int tok = g * 8 + sub;
            const float* xr = x + (size_t)tok * Dd;
            float acc[Ee];
#pragma unroll
            for (int e = 0; e < Ee; ++e) acc[e] = 0.f;
#pragma unroll
            for (int jj = 0; jj < 4; ++jj) {
                const int d0 = jj * 256 + lane * 4;
                float4 xv = *(const float4*)(xr + d0);
#pragma unroll
                for (int e = 0; e < Ee; ++e) {
                    float4 wv = *(const float4*)(&smem[e * 1028 + d0]);
                    acc[e] = fmaf(xv.x, wv.x, acc[e]);
                    acc[e] = fmaf(xv.y, wv.y, acc[e]);
                    acc[e] = fmaf(xv.z, wv.z, acc[e]);
                    acc[e] = fmaf(xv.w, wv.w, acc[e]);
                }
            }
#pragma unroll
            for (int e = 0; e < Ee; ++e) {
                float v = acc[e];
#pragma unroll
                for (int off = 32; off > 0; off >>= 1) v += __shfl_xor(v, off, 64);
                acc[e] = v + bg[e];
            }
            if (lane == 0) {
                int best = 0;
                float bv = acc[0];
#pragma unroll
                for (int e = 1; e < Ee; ++e)
                    if (acc[e] > bv) { bv = acc[e]; best = e; }   // strict > = jnp.argmax
                bb[sub] = 1 << best;
                const int n = tok & (Nn - 1);
                const int b = tok >> 9;
                if (n < 8) {
                    float m = acc[0];
#pragma unroll
                    for (int e = 1; e < Ee; ++e) m = fmaxf(m, acc[e]);
                    float s = 0.f;
#pragma unroll
                    for (int e = 0; e < Ee; ++e) s += expf(acc[e] - m);
                    gate0[b * 8 + n] = expf(acc[0] - m) / s;   // softmax prob of expert 0
                }
            }
        }
        __syncthreads();
        if (tid == 0) {
            int m = 0;
#pragma unroll
            for (int i = 0; i < 8; ++i) m |= bb[i];
            bmask[g] = m;
        }
    } else {
        // ---- zero dead output rows (n >= 8) ----
        const int z = blk - 512;
        const float4 zero4 = make_float4(0.f, 0.f, 0.f, 0.f);
#pragma unroll
        for (int r = 0; r < 8; ++r) {
            const int row = z * 8 + r;
            const int n = row & (Nn - 1);
            if (n >= 8)
                *(float4*)(out + (size_t)row * Dd + tid * 4) = zero4;
        }
    }
}

// =====================================================================
// K2: blocks [0,256) reduce p1 + bias + exact GELU -> hT[t][hh]
//     block 256: lane-parallel gate_scores + loss
// =====================================================================
__global__ __launch_bounds__(128) void k2_gelu_score(
    const float* __restrict__ p1, const float* __restrict__ b1,
    float* __restrict__ hT, const int* __restrict__ bmask,
    const float* __restrict__ gate0, float* __restrict__ gs,
    float* __restrict__ loss_out)
{
    const int blk = blockIdx.x, tid = threadIdx.x;
    if (blk < 256) {
        const int idx = blk * 128 + tid;              // 0..32767 (float4 granularity)
        const int hh0 = (idx << 2) & (Hh - 1);
        const int t = idx >> 10;
        float4 s = *(const float4*)(b1 + hh0);        // expert 0: b1[0][hh]
#pragma unroll
        for (int q = 0; q < P1S; ++q) {
            float4 v = *(const float4*)(p1 + ((size_t)(q * 32 + t)) * Hh + hh0);
            s.x += v.x; s.y += v.y; s.z += v.z; s.w += v.w;
        }
        const float c = 0.70710678118654752440f;
        float4 r;
        r.x = 0.5f * s.x * (1.f + erff(s.x * c));
        r.y = 0.5f * s.y * (1.f + erff(s.y * c));
        r.z = 0.5f * s.z * (1.f + erff(s.z * c));
        r.w = 0.5f * s.w * (1.f + erff(s.w * c));
        *(float4*)(hT + (size_t)t * Hh + hh0) = r;    // coalesced, t-major
    } else if (tid < 64) {
        const int l = tid;
        int m0 = bmask[l], m1 = bmask[64 + l], m2 = bmask[128 + l], m3 = bmask[192 + l];
#pragma unroll
        for (int off = 32; off > 0; off >>= 1) {
            m0 |= __shfl_xor(m0, off, 64);
            m1 |= __shfl_xor(m1, off, 64);
            m2 |= __shfl_xor(m2, off, 64);
            m3 |= __shfl_xor(m3, off, 64);
        }
        float gm = 0.f;
        if (l < 32) {
            const int b = l >> 3, n = l & 7;
            const int sm = (b == 0) ? m0 : (b == 1) ? m1 : (b == 2) ? m2 : m3;
            if ((sm >> n) & 1) gm = gate0[l];
        }
        float den = gm + __shfl_xor(gm, 8, 64);
        den += __shfl_xor(den, 16, 64);
        float gsv = 0.f;
        if (l < 32) { gsv = gm / (den + EPS) * CAP; gs[l] = gsv; }
        float impn = gsv + __shfl_xor(gsv, 8, 64); impn += __shfl_xor(impn, 16, 64);
        float ldv = (gsv > 0.f) ? 1.f : 0.f;
        float ldn = ldv + __shfl_xor(ldv, 8, 64); ldn += __shfl_xor(ldn, 16, 64);
        float si = gsv, sl = ldv;
#pragma unroll
        for (int off = 32; off > 0; off >>= 1) {
            si += __shfl_xor(si, off, 64);
            sl += __shfl_xor(sl, off, 64);
        }
        const float M = (float)(Nn * Ee);
        const float mi = si / M, ml = sl / M;
        float di = (l < 8) ? (impn - mi) * (impn - mi) : 0.f;
        float dl = (l < 8) ? (ldn - ml) * (ldn - ml) : 0.f;
#pragma unroll
        for (int off = 32; off > 0; off >>= 1) {
            di += __shfl_xor(di, off, 64);
            dl += __shfl_xor(dl, off, 64);
        }
        if (l == 0) {
            di += (M - 8.f) * mi * mi;
            dl += (M - 8.f) * ml * ml;
            const float vi = di / (M - 1.f), vl = dl / (M - 1.f);
            *loss_out = vi / (mi * mi + 1e-10f) + vl / (ml * ml + 1e-10f);
        }
    }
}

// =====================================================================
// K3: ffn2 GEMM. grid (8 d-chunks of 128, 32 k-splits of 128), 128 thr
// =====================================================================
__global__ __launch_bounds__(128) void k3_ffn2(
    const float* __restrict__ w2, const float* __restrict__ hT,
    float* __restrict__ p2)
{
    __shared__ float smem[128 * 32];     // [k][t]
    const int tid = threadIdx.x;
    const int ky = blockIdx.y;           // k-split 0..31
    {
        const int t = tid & 31, kq = tid >> 5;    // kq 0..3 (32 k each)
        const float* src = hT + (size_t)t * Hh + ky * 128 + kq * 32;
#pragma unroll
        for (int c = 0; c < 8; ++c) {
            float4 v = *(const float4*)(src + c * 4);
            smem[(kq * 32 + c * 4 + 0) * 32 + t] = v.x;
            smem[(kq * 32 + c * 4 + 1) * 32 + t] = v.y;
            smem[(kq * 32 + c * 4 + 2) * 32 + t] = v.z;
            smem[(kq * 32 + c * 4 + 3) * 32 + t] = v.w;
        }
    }
    __syncthreads();
    const int d = blockIdx.x * 128 + tid;
    const int k0 = ky * 128;
    const float* wp = w2 + (size_t)k0 * Dd + d;   // expert 0: w2[h][d]
    float acc[32];
#pragma unroll
    for (int t = 0; t < 32; ++t) acc[t] = 0.f;
#pragma unroll
    for (int q = 0; q < 8; ++q) {
        float wbuf[16];
#pragma unroll
        for (int kk = 0; kk < 16; ++kk)
            wbuf[kk] = wp[(size_t)(q * 16 + kk) * Dd];
#pragma unroll
        for (int kk = 0; kk < 16; ++kk) {
            const float4* xrow = (const float4*)(smem + (q * 16 + kk) * 32);
            const float w = wbuf[kk];
#pragma unroll
            for (int t4 = 0; t4 < 8; ++t4) {
                float4 xv = xrow[t4];
                acc[t4 * 4 + 0] = fmaf(xv.x, w, acc[t4 * 4 + 0]);
                acc[t4 * 4 + 1] = fmaf(xv.y, w, acc[t4 * 4 + 1]);
                acc[t4 * 4 + 2] = fmaf(xv.z, w, acc[t4 * 4 + 2]);
                acc[t4 * 4 + 3] = fmaf(xv.w, w, acc[t4 * 4 + 3]);
            }
        }
    }
    float* o = p2 + ((size_t)ky * 32) * Dd + d;
#pragma unroll
    for (int t = 0; t < 32; ++t) { *o = acc[t]; o += Dd; }
}

// =====================================================================
// K4: reduce p2 + bias + gate scale for the 32 live rows. 64 blk x 128
// =====================================================================
__global__ __launch_bounds__(128) void k4_out(
    const float* __restrict__ p2, const float* __restrict__ b2,
    const float* __restrict__ gs, float* __restrict__ out)
{
    const int t = blockIdx.x >> 1;
    const int d4 = (blockIdx.x & 1) * 512 + threadIdx.x * 4;
    float4 a = make_float4(0.f, 0.f, 0.f, 0.f);
    const float* p = p2 + (size_t)t * Dd + d4;
#pragma unroll 8
    for (int s = 0; s < P2S; ++s) {
        float4 v = *(const float4*)p;
        p += (size_t)32 * Dd;
        a.x += v.x; a.y += v.y; a.z += v.z; a.w += v.w;
    }
    float4 bbv = *(const float4*)(b2 + d4);       // expert 0: b2[0][d]
    const float g = gs[t];
    const int b = t >> 3, n = t & 7;
    float4 o;
    o.x = g * (a.x + bbv.x);
    o.y = g * (a.y + bbv.y);
    o.z = g * (a.z + bbv.z);
    o.w = g * (a.w + bbv.w);
    *(float4*)(out + ((size_t)(b * Nn + n)) * Dd + d4) = o;
}

extern "C" void kernel_launch(void* const* d_in, const int* in_sizes, int n_in,
                              void* d_out, int out_size, void* d_ws, size_t ws_size,
                              hipStream_t stream) {
    const float* x  = (const float*)d_in[0];
    const float* wg = (const float*)d_in[1];
    const float* bg = (const float*)d_in[2];
    const float* w1 = (const float*)d_in[3];
    const float* b1 = (const float*)d_in[4];
    const float* w2 = (const float*)d_in[5];
    const float* b2 = (const float*)d_in[6];
    float* out = (float*)d_out;
    float* wsf = (float*)d_ws;

    int*   bmask = (int*)d_ws;
    float* gate0 = wsf + 256;
    float* gs    = wsf + 320;
    float* hT    = wsf + 512;
    float* p1    = wsf + 132096;
    float* p2    = wsf + 4326400;

    k1_gate_ffn1<<<dim3(768), dim3(256), 0, stream>>>(x, wg, bg, w1, bmask, gate0, p1, out);
    k2_gelu_score<<<dim3(257), dim3(128), 0, stream>>>(p1, b1, hT, bmask, gate0, gs,
                                                       out + (out_size - 1));
    k3_ffn2<<<dim3(8, 32), dim3(128), 0, stream>>>(w2, hT, p2);
    k4_out<<<dim3(64), dim3(128), 0, stream>>>(p2, b2, gs, out);
}